// Round 4
// baseline (3286.987 us; speedup 1.0000x reference)
//
#include <hip/hip_runtime.h>
#include <math.h>

#define N   2048
#define NT  256

// stable logaddexp (fallback kernel only)
__device__ __forceinline__ float lae(float a, float b) {
    float m  = fmaxf(a, b);
    float mn = fminf(a, b);
    return m + log1pf(expf(mn - m));
}

// exact integer block weight: sum_{j=h}^{e} (N-j)
__device__ __forceinline__ int wsum(int h, int e) {
    return (((N - h) + (N - e)) * (e - h + 1)) >> 1;
}

// ============================================================================
// Kernel 1: per-row bitonic sort, packed u64 (desc-sortable key | index).
// Stable: ties broken by ascending original index == jnp.argsort(-theta).
// ============================================================================
__global__ void __launch_bounds__(NT)
sort_kernel(const float* __restrict__ x1, const float* __restrict__ x2,
            int nrows, float* __restrict__ ss, unsigned short* __restrict__ sidx)
{
    __shared__ unsigned long long s_kv[N];   // 16 KB

    const int rid = blockIdx.x;
    const int tid = threadIdx.x;
    const float* __restrict__ x = (rid < nrows) ? x1 : x2;
    const size_t base = (size_t)(rid < nrows ? rid : rid - nrows) * N;

    for (int j = tid; j < N; j += NT) {
        float th = x[base + j] * 10.0f;              // theta = x / EPS
        unsigned int u = __float_as_uint(th);
        unsigned int a = (u & 0x80000000u) ? ~u : (u ^ 0x80000000u); // asc-sortable
        s_kv[j] = ((unsigned long long)(~a) << 32) | (unsigned int)j; // desc key
    }
    __syncthreads();

    for (int k = 2; k <= N; k <<= 1) {
        for (int jj = k >> 1; jj > 0; jj >>= 1) {
            for (int i = tid; i < N; i += NT) {
                int l = i ^ jj;
                if (l > i) {
                    unsigned long long a = s_kv[i], b = s_kv[l];
                    unsigned long long mn = (a < b) ? a : b;
                    unsigned long long mx = (a < b) ? b : a;
                    bool up = ((i & k) == 0);
                    s_kv[i] = up ? mn : mx;          // ascending by kv = descending theta
                    s_kv[l] = up ? mx : mn;
                }
            }
            __syncthreads();
        }
    }

    float* __restrict__ so = ss + (size_t)rid * N;
    unsigned short* __restrict__ io = sidx + (size_t)rid * N;
    for (int j = tid; j < N; j += NT) {
        unsigned long long kv = s_kv[j];
        unsigned int a = ~(unsigned int)(kv >> 32);
        unsigned int u = (a & 0x80000000u) ? (a ^ 0x80000000u) : ~a;
        so[j] = __uint_as_float(u);
        io[j] = (unsigned short)(kv & 0xFFFFu);
    }
}

// ============================================================================
// Kernel 2: lane-per-row exp-domain stack PAV.
// One lane owns one row: 64 rows per wave, all lanes active.
// Stack in global [depth][rid] (coalesced, L2-resident hot window).
// Entry = fp32 Y with 11-bit block head round-packed into low mantissa bits.
// Top-2 entries cached in registers. Input row register-prefetched (float4x4).
// Ends by overwriting the row IN PLACE with r_sorted = exp(theta)*W/Y.
// ============================================================================
__global__ void __launch_bounds__(64)
pav_lane_kernel(float* __restrict__ ss, unsigned int* __restrict__ stk, int total)
{
    const int rid = blockIdx.x * 64 + threadIdx.x;
    if (rid >= total) return;
    float* __restrict__ row = ss + (size_t)rid * N;
    const float4* __restrict__ rowv = (const float4*)row;

    float4 c0 = rowv[0], c1 = rowv[1], c2 = rowv[2], c3 = rowv[3];

    int   sp  = 0;
    float t0Y = 0.f, t1Y = 0.f;   // top / below-top register cache
    int   t0h = 0,   t1h = 0;

    for (int g = 0; g < N / 16; ++g) {
        float4 n0 = c0, n1 = c1, n2 = c2, n3 = c3;
        if (g + 1 < N / 16) {                 // prefetch next 16 elements
            n0 = rowv[(g + 1) * 4 + 0];
            n1 = rowv[(g + 1) * 4 + 1];
            n2 = rowv[(g + 1) * 4 + 2];
            n3 = rowv[(g + 1) * 4 + 3];
        }
        float vals[16] = {c0.x, c0.y, c0.z, c0.w, c1.x, c1.y, c1.z, c1.w,
                          c2.x, c2.y, c2.z, c2.w, c3.x, c3.y, c3.z, c3.w};
        #pragma unroll
        for (int q = 0; q < 16; ++q) {
            const int j  = g * 16 + q;
            float E   = __expf(vals[q]);
            float cY  = E;
            int   ch  = j;
            int   cWi = N - j;                 // wsum(j, j)
            float cWf = (float)cWi;
            while (sp > 0) {
                int tWi = wsum(t0h, ch - 1);   // top block: head t0h, end ch-1
                if (t0Y * cWf > cY * (float)tWi) break;   // strictly decreasing
                // pool top into current
                cY += t0Y;
                ch  = t0h;
                cWi = wsum(ch, j);
                cWf = (float)cWi;
                --sp;
                t0Y = t1Y; t0h = t1h;
                if (sp >= 2) {                 // refill below-top lookahead
                    unsigned u = stk[(size_t)(sp - 2) * total + rid];
                    t1h = (int)(u & 0x7FFu);
                    t1Y = __uint_as_float(u & 0xFFFFF800u);
                }
            }
            // push current block (round-to-nearest mantissa pack, head in low 11 bits)
            unsigned pu = ((__float_as_uint(cY) + 0x400u) & 0xFFFFF800u) | (unsigned)ch;
            stk[(size_t)sp * total + rid] = pu;
            ++sp;
            t1Y = t0Y; t1h = t0h;
            t0Y = __uint_as_float(pu & 0xFFFFF800u);
            t0h = ch;
        }
        c0 = n0; c1 = n1; c2 = n2; c3 = n3;
    }

    // ---- expansion in place: walk blocks backward (end known), r = exp(th)*W/Y
    int e = N - 1;
    for (int b = sp - 1; b >= 0; --b) {
        unsigned u = stk[(size_t)b * total + rid];
        int   h = (int)(u & 0x7FFu);
        float Y = __uint_as_float(u & 0xFFFFF800u);
        float c = (float)wsum(h, e) / Y;
        for (int j = h; j <= e; ++j) {
            row[j] = __expf(row[j]) * c;
        }
        e = h - 1;
    }
}

// ============================================================================
// Kernel 3: fused scatter + correlation. r1 scattered to original order via
// LDS; r2 gathered against it. S/Q sums are permutation-invariant.
// ============================================================================
__global__ void __launch_bounds__(NT)
corr_fused_kernel(const float* __restrict__ rsorted,
                  const unsigned short* __restrict__ sidx,
                  int nrows, float* __restrict__ out)
{
    __shared__ float s_r1[N];
    __shared__ float s_red[NT / 64][5];
    const int p   = blockIdx.x;
    const int tid = threadIdx.x;
    const float*          r1 = rsorted + (size_t)p * N;
    const float*          r2 = rsorted + (size_t)(p + nrows) * N;
    const unsigned short* i1 = sidx + (size_t)p * N;
    const unsigned short* i2 = sidx + (size_t)(p + nrows) * N;

    float S1 = 0.f, Q1 = 0.f, S2 = 0.f, Q2 = 0.f, P = 0.f;
    for (int j = tid; j < N; j += NT) {
        float a = r1[j];
        s_r1[i1[j]] = a;
        S1 += a; Q1 += a * a;
    }
    __syncthreads();
    for (int j = tid; j < N; j += NT) {
        float b = r2[j];
        float a = s_r1[i2[j]];
        S2 += b; Q2 += b * b; P += a * b;
    }

    #pragma unroll
    for (int off = 32; off > 0; off >>= 1) {
        S1 += __shfl_down(S1, off);
        Q1 += __shfl_down(Q1, off);
        S2 += __shfl_down(S2, off);
        Q2 += __shfl_down(Q2, off);
        P  += __shfl_down(P,  off);
    }
    const int wid = tid >> 6, lane = tid & 63;
    if (lane == 0) {
        s_red[wid][0] = S1; s_red[wid][1] = Q1; s_red[wid][2] = S2;
        s_red[wid][3] = Q2; s_red[wid][4] = P;
    }
    __syncthreads();
    if (tid == 0) {
        for (int w = 1; w < NT / 64; ++w) {
            S1 += s_red[w][0]; Q1 += s_red[w][1]; S2 += s_red[w][2];
            Q2 += s_red[w][3]; P  += s_red[w][4];
        }
        const float inv_n = 1.0f / (float)N;
        float num = P  - S1 * S2 * inv_n;
        float d1  = Q1 - S1 * S1 * inv_n;
        float d2  = Q2 - S2 * S2 * inv_n;
        out[p] = 1.0f - num / sqrtf(d1 * d2);
    }
}

// ============================================================================
// Fallback: validated monolithic kernel (used only if ws too small)
// ============================================================================
__global__ void __launch_bounds__(NT)
soft_spearman_mono(const float* __restrict__ x1,
                   const float* __restrict__ x2,
                   float* __restrict__ out)
{
    __shared__ float s_key[N];
    __shared__ int   s_idx[N];
    __shared__ float s_r1[N];
    __shared__ float s_ly[N];
    __shared__ float s_lw[N];
    __shared__ float s_sol[N];
    __shared__ int   s_tgt[N];
    __shared__ int   s_nb;
    __shared__ float s_red[NT / 64][5];

    const int row = blockIdx.x;
    const int tid = threadIdx.x;

    float S1 = 0.f, Q1 = 0.f, S2 = 0.f, Q2 = 0.f, P = 0.f;

    for (int phase = 0; phase < 2; ++phase) {
        const float* __restrict__ x = (phase == 0) ? x1 : x2;
        const size_t base = (size_t)row * N;

        for (int j = tid; j < N; j += NT) {
            s_key[j] = x[base + j] * 10.0f;
            s_idx[j] = j;
        }
        __syncthreads();

        for (int k = 2; k <= N; k <<= 1) {
            for (int jj = k >> 1; jj > 0; jj >>= 1) {
                for (int i = tid; i < N; i += NT) {
                    int l = i ^ jj;
                    if (l > i) {
                        float ki = s_key[i], kl = s_key[l];
                        bool sw = ((i & k) == 0) ? (ki < kl) : (ki > kl);
                        if (sw) {
                            s_key[i] = kl; s_key[l] = ki;
                            int t = s_idx[i]; s_idx[i] = s_idx[l]; s_idx[l] = t;
                        }
                    }
                }
                __syncthreads();
            }
        }

        for (int j = tid; j < N; j += NT) {
            float y = s_key[j];
            float w = logf((float)(N - j));
            s_ly[j]  = y;
            s_lw[j]  = w;
            s_sol[j] = y - w;
            s_tgt[j] = j;
        }
        __syncthreads();

        if (tid == 0) {
            int i = 0;
            while (i < N) {
                int k = s_tgt[i] + 1;
                if (k >= N) break;
                if (s_sol[i] > s_sol[k]) { i = k; continue; }
                float sol_prev = s_sol[i];
                for (;;) {
                    float ly = lae(s_ly[i], s_ly[k]);
                    float lw = lae(s_lw[i], s_lw[k]);
                    s_ly[i] = ly; s_lw[i] = lw; s_sol[i] = ly - lw;
                    int kn = s_tgt[k] + 1;
                    if (kn >= N || sol_prev > s_sol[kn]) {
                        s_tgt[i] = kn - 1;
                        s_tgt[kn - 1] = i;
                        if (i > 0) i = s_tgt[i - 1];
                        break;
                    }
                    k = kn;
                }
            }
            int nb = 0, h = 0;
            while (h < N) {
                int e  = s_tgt[h];
                int hh = h;
                h = e + 1;
                s_tgt[nb++] = hh;
            }
            s_nb = nb;
        }
        __syncthreads();

        const int nb = s_nb;
        for (int j = tid; j < N; j += NT) {
            int lo = 0, hi = nb - 1;
            while (lo < hi) {
                int mid = (lo + hi + 1) >> 1;
                if (s_tgt[mid] <= j) lo = mid; else hi = mid - 1;
            }
            float r = expf(s_key[j] - s_sol[s_tgt[lo]]);
            int   v = s_idx[j];
            if (phase == 0) {
                s_r1[v] = r;
                S1 += r; Q1 += r * r;
            } else {
                float a = s_r1[v];
                S2 += r; Q2 += r * r; P += a * r;
            }
        }
        __syncthreads();
    }

    #pragma unroll
    for (int off = 32; off > 0; off >>= 1) {
        S1 += __shfl_down(S1, off);
        Q1 += __shfl_down(Q1, off);
        S2 += __shfl_down(S2, off);
        Q2 += __shfl_down(Q2, off);
        P  += __shfl_down(P,  off);
    }
    const int wid = tid >> 6, lane = tid & 63;
    if (lane == 0) {
        s_red[wid][0] = S1; s_red[wid][1] = Q1; s_red[wid][2] = S2;
        s_red[wid][3] = Q2; s_red[wid][4] = P;
    }
    __syncthreads();
    if (tid == 0) {
        for (int w = 1; w < NT / 64; ++w) {
            S1 += s_red[w][0]; Q1 += s_red[w][1]; S2 += s_red[w][2];
            Q2 += s_red[w][3]; P  += s_red[w][4];
        }
        const float inv_n = 1.0f / (float)N;
        float num = P  - S1 * S2 * inv_n;
        float d1  = Q1 - S1 * S1 * inv_n;
        float d2  = Q2 - S2 * S2 * inv_n;
        out[row] = 1.0f - num / sqrtf(d1 * d2);
    }
}

extern "C" void kernel_launch(void* const* d_in, const int* in_sizes, int n_in,
                              void* d_out, int out_size, void* d_ws, size_t ws_size,
                              hipStream_t stream) {
    const float* x1 = (const float*)d_in[0];
    const float* x2 = (const float*)d_in[1];
    float* out = (float*)d_out;
    const int nrows = in_sizes[0] / N;        // 4096
    const int total = 2 * nrows;              // 8192 (row,phase) pairs

    const size_t SZ_S = (size_t)total * N * sizeof(float);          // sorted theta -> ranks (in place)
    const size_t SZ_I = (size_t)total * N * sizeof(unsigned short); // sorted indices
    const size_t SZ_K = (size_t)total * N * sizeof(unsigned int);   // PAV stack [depth][rid]
    const size_t need = SZ_S + SZ_I + SZ_K;

    if (ws_size >= need) {
        float*          ss   = (float*)d_ws;
        unsigned short* sidx = (unsigned short*)((char*)d_ws + SZ_S);
        unsigned int*   stk  = (unsigned int*)((char*)d_ws + SZ_S + SZ_I);

        sort_kernel<<<total, NT, 0, stream>>>(x1, x2, nrows, ss, sidx);
        pav_lane_kernel<<<total / 64, 64, 0, stream>>>(ss, stk, total);
        corr_fused_kernel<<<nrows, NT, 0, stream>>>(ss, sidx, nrows, out);
    } else {
        soft_spearman_mono<<<nrows, NT, 0, stream>>>(x1, x2, out);
    }
}